// Round 7
// baseline (2888.556 us; speedup 1.0000x reference)
//
#include <hip/hip_runtime.h>
#include <math.h>

#define N 4096
#define STEPS 16384
#define CHUNK 16
#define NCHUNK (STEPS / CHUNK)
#define MBLK 1024
#define SST 20   // padded stride (floats) for ST/XT: float4-aligned, 2-way max (free)

// Workgroup barrier that does NOT drain vmcnt (LDS-only ordering between phases).
__device__ __forceinline__ void lgkm_barrier() {
  asm volatile("s_waitcnt lgkmcnt(0)\n\ts_barrier" ::: "memory");
}

// ---- prep: thr[t] = atanh(2u-1) in fp64; lastocc[t] = no later same-idx in chunk ----
__global__ __launch_bounds__(256) void pre_kernel(const float* __restrict__ u,
                                                  const int* __restrict__ idx,
                                                  double* __restrict__ thr,
                                                  int* __restrict__ lastocc) {
  int t = blockIdx.x * 256 + threadIdx.x;
  if (t < STEPS) {
    float r = 2.0f * u[t] - 1.0f;          // exact same fp32 rounding as reference
    double rd = (double)r;
    thr[t] = 0.5 * log((1.0 + rd) / (1.0 - rd));   // r=-1 -> -inf (tie->+1 matches ref)
    int cbase = t & ~(CHUNK - 1);
    int my = idx[t];
    int lo = 1;
    for (int tt = (t & (CHUNK - 1)) + 1; tt < CHUNK; ++tt)
      if (idx[cbase + tt] == my) { lo = 0; break; }
    lastocc[t] = lo;
  }
}

// ---- initial field: I0[row] = sum_k J[row,k]*m0[k] + h[row], fp64 accumulate ----
__global__ __launch_bounds__(256) void init_field_kernel(const float* __restrict__ J,
                                                         const float* __restrict__ h,
                                                         const float* __restrict__ m0,
                                                         double* __restrict__ I) {
  __shared__ double red[256];
  int row = blockIdx.x;
  const float4* Jr = (const float4*)(J + (size_t)row * N);
  const float4* mv = (const float4*)m0;
  double acc = 0.0;
  for (int q = threadIdx.x; q < N / 4; q += 256) {
    float4 a = Jr[q];
    float4 b = mv[q];
    acc += (double)(a.x * b.x) + (double)(a.y * b.y) +
           (double)(a.z * b.z) + (double)(a.w * b.w);
  }
  red[threadIdx.x] = acc;
  __syncthreads();
  for (int s = 128; s > 0; s >>= 1) {
    if (threadIdx.x < s) red[threadIdx.x] += red[threadIdx.x + s];
    __syncthreads();
  }
  if (threadIdx.x == 0) I[row] = red[0] + (double)h[row];
}

// ---- overlapped Glauber chain: 1 workgroup, 1024 threads, ONE barrier/chunk ----
// Iteration c (parity par=c&1):
//   wave0: resolves chunk c. base = fld[par][mi] (state <= c-2; P2 concurrently
//          writes the OTHER parity) + exact f64 corr = sum_j X1(c)[j][t]*dprev[j]
//          (dprev = delta(c-1), wave0 registers). Publishes compacted flips to
//          pub[par]; S(c+2)/X1(c+2) gathered 2 chunks ahead (pv pipeline).
//   waves 1-15: apply delta(c-1) from pub[1-par]; write-through fld[1-par]
//          (state <= c-1) iff F(c-1)>0 || F(c-2)>0 (buffer-staleness tracking).
// Field pair-split ownership (conflict-free b128 writes): thread u=tid-64 owns
// cols {256+2u,257+2u} and {2176+2u,2177+2u}; threads 64..319 also own col u.
__global__ __launch_bounds__(MBLK) void pbit_kernel(const float* __restrict__ J,
                                                    const float* __restrict__ m0,
                                                    const int* __restrict__ idx,
                                                    const double* __restrict__ thr,
                                                    const int* __restrict__ lastocc,
                                                    const double* __restrict__ I0,
                                                    float* __restrict__ out) {
  __shared__ __align__(16) double fld_lds[2][N];         // 64 KB parity field
  __shared__ __align__(16) float m_lds[N];               // 16 KB spins
  __shared__ __align__(16) float ST_lds[2][CHUNK * SST]; // S(c) col-major dbuf
  __shared__ __align__(16) float XT_lds[2][CHUNK * SST]; // X1(c) col-major dbuf
  __shared__ __align__(16) int   pubi_lds[2][CHUNK];     // compacted flip rows
  __shared__ __align__(16) float pubd_lds[2][CHUNK];     // compacted deltas
  __shared__ int pubF_lds[2];                            // flip counts

  const int tid = threadIdx.x;
  const bool isW0 = (tid < 64);
  const int u = tid - 64;
  const int cA = 256 + 2 * u;
  const int cB = 2176 + 2 * u;
  const bool hasX = (tid >= 64) && (tid < 320);   // waves 1-4: extra col u

  double iA0 = 0, iA1 = 0, iB0 = 0, iB1 = 0, ixv = 0;
  if (!isW0) {
    iA0 = I0[cA]; iA1 = I0[cA + 1];
    iB0 = I0[cB]; iB1 = I0[cB + 1];
    *(double2*)(&fld_lds[0][cA]) = make_double2(iA0, iA1);
    *(double2*)(&fld_lds[1][cA]) = make_double2(iA0, iA1);
    *(double2*)(&fld_lds[0][cB]) = make_double2(iB0, iB1);
    *(double2*)(&fld_lds[1][cB]) = make_double2(iB0, iB1);
    if (hasX) { ixv = I0[u]; fld_lds[0][u] = ixv; fld_lds[1][u] = ixv; }
  }
  ((float4*)m_lds)[tid] = ((const float4*)m0)[tid];

  const int t16 = tid & 15;       // step slot within chunk
  const int gt = tid >> 2;        // gather row slot (wave0: 0..15)
  const int gq = (tid & 3) * 4;   // gather col group

  // wave0 pipeline registers
  int mi = 0, ni = 0, mlo = 0, nlo = 0;
  double mt = 0.0, nt = 0.0;
  int growS = 0, growX = 0, gc0 = 0, gc1 = 0, gc2 = 0, gc3 = 0;
  float pvS0 = 0, pvS1 = 0, pvS2 = 0, pvS3 = 0;
  float pvX0 = 0, pvX1 = 0, pvX2 = 0, pvX3 = 0;
  float mym = 0.0f, dprev = 0.0f;

  if (isW0) {
    mi = idx[t16];      mt = thr[t16];      mlo = lastocc[t16];
    ni = idx[16 + t16]; nt = thr[16 + t16]; nlo = lastocc[16 + t16];
    growS = idx[32 + gt];   // S rows for chunk 2
    growX = idx[16 + gt];   // X rows for chunk 2 = idx of chunk 1
    gc0 = idx[32 + gq];     gc1 = idx[32 + gq + 1];
    gc2 = idx[32 + gq + 2]; gc3 = idx[32 + gq + 3];
    // zero XT bufs (chunk 0 corr multiplies by dprev=0; must be finite)
    for (int k = tid; k < CHUNK * SST; k += 64) {
      XT_lds[0][k] = 0.0f; XT_lds[1][k] = 0.0f;
    }
    // sync gather S(0) -> buf 0
    {
      int r0 = idx[gt];
      int c0 = idx[gq], c1 = idx[gq + 1], c2 = idx[gq + 2], c3 = idx[gq + 3];
      const float* Jr = J + (size_t)r0 * N;
      ST_lds[0][(gq + 0) * SST + gt] = Jr[c0];
      ST_lds[0][(gq + 1) * SST + gt] = Jr[c1];
      ST_lds[0][(gq + 2) * SST + gt] = Jr[c2];
      ST_lds[0][(gq + 3) * SST + gt] = Jr[c3];
    }
    // pv pipeline preload: S(1) rows idx_1, X(1) rows idx_0, cols idx_1
    {
      int rS = idx[16 + gt], rX = idx[gt];
      int d0 = idx[16 + gq],     d1 = idx[16 + gq + 1];
      int d2 = idx[16 + gq + 2], d3 = idx[16 + gq + 3];
      const float* JS = J + (size_t)rS * N;
      pvS0 = JS[d0]; pvS1 = JS[d1]; pvS2 = JS[d2]; pvS3 = JS[d3];
      const float* JX = J + (size_t)rX * N;
      pvX0 = JX[d0]; pvX1 = JX[d1]; pvX2 = JX[d2]; pvX3 = JX[d3];
    }
    if (tid == 0) { pubF_lds[0] = 0; pubF_lds[1] = 0; }
  }
  __syncthreads();
  if (isW0) mym = m_lds[mi];

  int Fm2 = 0;   // P2: F of the chunk before last (buffer staleness tracker)

  for (int cc = 0; cc < NCHUNK; cc += 2) {
#pragma unroll
    for (int q = 0; q < 2; ++q) {       // par = q (cc even)
      const int c = cc + q;
      if (isW0) {
        // ---- resolve chunk c (concurrent with P2 applying c-1) ----
        // 1) issue S/X gathers for c+2 (pv-stored next iter, read in 2 iters)
        const float* Sp = J + (size_t)growS * N;
        float cvS0 = Sp[gc0], cvS1 = Sp[gc1], cvS2 = Sp[gc2], cvS3 = Sp[gc3];
        const float* Xp = J + (size_t)growX * N;
        float cvX0 = Xp[gc0], cvX1 = Xp[gc1], cvX2 = Xp[gc2], cvX3 = Xp[gc3];
        // 2) staged loads: t16-view for c+2; gather-addr view for c+3
        int b2 = c * CHUNK + 32; if (b2 >= STEPS) b2 = 0;
        int b3 = c * CHUNK + 48; if (b3 >= STEPS) b3 = 0;
        int Li = idx[b2 + t16];
        double Lt = thr[b2 + t16];
        int Llo = lastocc[b2 + t16];
        int Lrow = idx[b3 + gt];
        int Lc0 = idx[b3 + gq];     int Lc1 = idx[b3 + gq + 1];
        int Lc2 = idx[b3 + gq + 2]; int Lc3 = idx[b3 + gq + 3];
        // 3) LDS reads: base field (<= c-2), S col, X col
        double Ival = fld_lds[q][mi];
        const float* sp = &ST_lds[q][t16 * SST];
        float4 sa = *(const float4*)(sp + 0);
        float4 sb = *(const float4*)(sp + 4);
        float4 sc = *(const float4*)(sp + 8);
        float4 sd = *(const float4*)(sp + 12);
        const float* xp = &XT_lds[q][t16 * SST];
        float4 xa = *(const float4*)(xp + 0);
        float4 xb = *(const float4*)(xp + 4);
        float4 xc = *(const float4*)(xp + 8);
        float4 xd = *(const float4*)(xp + 12);
        // 4) store pv = S(c+1)/X(c+1) into bufs[1-q] (issued a full chunk ago)
        ST_lds[1 - q][(gq + 0) * SST + gt] = pvS0;
        ST_lds[1 - q][(gq + 1) * SST + gt] = pvS1;
        ST_lds[1 - q][(gq + 2) * SST + gt] = pvS2;
        ST_lds[1 - q][(gq + 3) * SST + gt] = pvS3;
        XT_lds[1 - q][(gq + 0) * SST + gt] = pvX0;
        XT_lds[1 - q][(gq + 1) * SST + gt] = pvX1;
        XT_lds[1 - q][(gq + 2) * SST + gt] = pvX2;
        XT_lds[1 - q][(gq + 3) * SST + gt] = pvX3;
        // 5) lag-1 correction: corr = sum_j X[j][t16] * dprev[j] (exact products,
        // f64 tree; dprev broadcast via immediate readlane)
#define DL(j) __int_as_float(__builtin_amdgcn_readlane(__float_as_int(dprev), (j)))
        double c0d = ((double)(xa.x * DL(0)) + (double)(xa.y * DL(1)))
                   + ((double)(xa.z * DL(2)) + (double)(xa.w * DL(3)));
        double c1d = ((double)(xb.x * DL(4)) + (double)(xb.y * DL(5)))
                   + ((double)(xb.z * DL(6)) + (double)(xb.w * DL(7)));
        double c2d = ((double)(xc.x * DL(8)) + (double)(xc.y * DL(9)))
                   + ((double)(xc.z * DL(10)) + (double)(xc.w * DL(11)));
        double c3d = ((double)(xd.x * DL(12)) + (double)(xd.y * DL(13)))
                   + ((double)(xd.z * DL(14)) + (double)(xd.w * DL(15)));
#undef DL
        Ival += (c0d + c1d) + (c2d + c3d);
        // 6) flip-driven serial resolve: rounds = flips + 1
        float mcur = mym;
        float finals = 0.0f, finald = 0.0f;
        int conf = -1;
        bool locked = false;
        while (true) {
          float s = (Ival >= mt) ? 1.0f : -1.0f;  // I >= atanh(r) <=> tanh(I) >= r
          float dl = s - mcur;
          unsigned long long mask = __ballot(dl != 0.0f) & 0xFFFFull;
          mask &= (~0ull) << (conf + 1);
          if (mask == 0) {
            if (!locked) { finals = s; finald = 0.0f; }
            break;
          }
          int f = (int)__builtin_ctzll(mask);     // wave-uniform
          if (!locked && t16 <= f) { finals = s; finald = dl; locked = true; }
          float dl_f = __int_as_float(__builtin_amdgcn_readlane(__float_as_int(dl), f));
          float s_f  = __int_as_float(__builtin_amdgcn_readlane(__float_as_int(s), f));
          int   i_f  = __builtin_amdgcn_readlane(mi, f);
          float4 ph = (f & 8) ? ((f & 4) ? sd : sc) : ((f & 4) ? sb : sa);
          float xcol = (f & 2) ? ((f & 1) ? ph.w : ph.z)
                               : ((f & 1) ? ph.y : ph.x);
          Ival += (double)(xcol * dl_f);          // exact product: dl in {-2,2}
          if (mi == i_f) mcur = s_f;              // in-chunk duplicate index
          conf = f;
        }
        // 7) publish: compacted flip list (parity q) + m updates
        unsigned long long fm = __ballot((tid < 16) && (finald != 0.0f));
        if (tid < 16) {
          if (finald != 0.0f) {
            int pos = __popcll(fm & ((1ull << t16) - 1ull));
            pubi_lds[q][pos] = mi;
            pubd_lds[q][pos] = finald;
          }
          if (mlo) m_lds[mi] = finals;
          if (tid == 0) pubF_lds[q] = __popcll(fm);
        }
        dprev = finald;
        // 8) m gather for next chunk (same wave, ordered after m writes)
        mym = m_lds[ni];
        // 9) rotate pipeline registers
        mi = ni; mt = nt; mlo = nlo;
        ni = Li; nt = Lt; nlo = Llo;
        growX = growS; growS = Lrow;
        gc0 = Lc0; gc1 = Lc1; gc2 = Lc2; gc3 = Lc3;
        pvS0 = cvS0; pvS1 = cvS1; pvS2 = cvS2; pvS3 = cvS3;
        pvX0 = cvX0; pvX1 = cvX1; pvX2 = cvX2; pvX3 = cvX3;
      } else {
        // ---- apply chunk c-1 (pub parity 1-q, field parity 1-q) ----
        const int pp = 1 - q;
        int F = pubF_lds[pp];
        if (F > 0) {
          int4 ra = *(const int4*)(&pubi_lds[pp][0]);
          int4 rb = *(const int4*)(&pubi_lds[pp][4]);
          int4 rc = *(const int4*)(&pubi_lds[pp][8]);
          int4 rd = *(const int4*)(&pubi_lds[pp][12]);
          float4 pa = *(const float4*)(&pubd_lds[pp][0]);
          float4 pb = *(const float4*)(&pubd_lds[pp][4]);
          float4 pc = *(const float4*)(&pubd_lds[pp][8]);
          float4 pd = *(const float4*)(&pubd_lds[pp][12]);
          int rows[CHUNK] = {ra.x, ra.y, ra.z, ra.w, rb.x, rb.y, rb.z, rb.w,
                             rc.x, rc.y, rc.z, rc.w, rd.x, rd.y, rd.z, rd.w};
          float dv[CHUNK] = {pa.x, pa.y, pa.z, pa.w, pb.x, pb.y, pb.z, pb.w,
                             pc.x, pc.y, pc.z, pc.w, pd.x, pd.y, pd.z, pd.w};
          float aA0 = 0.f, aA1 = 0.f, aB0 = 0.f, aB1 = 0.f, ax = 0.f;
          {
            float2 rA[8], rB[8]; float rx[8];
#pragma unroll
            for (int t = 0; t < 8; ++t)
              if (t < F) {
                const float* rp = J + (size_t)rows[t] * N;
                rA[t] = *(const float2*)(rp + cA);
                rB[t] = *(const float2*)(rp + cB);
                if (hasX) rx[t] = rp[u];
              }
#pragma unroll
            for (int t = 0; t < 8; ++t)
              if (t < F) {
                aA0 += rA[t].x * dv[t]; aA1 += rA[t].y * dv[t];
                aB0 += rB[t].x * dv[t]; aB1 += rB[t].y * dv[t];
                if (hasX) ax += rx[t] * dv[t];
              }
          }
          if (F > 8) {
            float2 rA[8], rB[8]; float rx[8];
#pragma unroll
            for (int t = 8; t < 16; ++t)
              if (t < F) {
                const float* rp = J + (size_t)rows[t] * N;
                rA[t - 8] = *(const float2*)(rp + cA);
                rB[t - 8] = *(const float2*)(rp + cB);
                if (hasX) rx[t - 8] = rp[u];
              }
#pragma unroll
            for (int t = 8; t < 16; ++t)
              if (t < F) {
                aA0 += rA[t - 8].x * dv[t]; aA1 += rA[t - 8].y * dv[t];
                aB0 += rB[t - 8].x * dv[t]; aB1 += rB[t - 8].y * dv[t];
                if (hasX) ax += rx[t - 8] * dv[t];
              }
          }
          iA0 += (double)aA0; iA1 += (double)aA1;
          iB0 += (double)aB0; iB1 += (double)aB1;
          if (hasX) ixv += (double)ax;
        }
        // write-through iff this parity buffer is stale (delta in last 2 chunks)
        if (F > 0 || Fm2 > 0) {
          *(double2*)(&fld_lds[pp][cA]) = make_double2(iA0, iA1);  // lane-contig 16B
          *(double2*)(&fld_lds[pp][cB]) = make_double2(iB0, iB1);  // conflict-free
          if (hasX) fld_lds[pp][u] = ixv;
        }
        Fm2 = F;
      }
      lgkm_barrier();
    }
  }

  ((float4*)out)[tid] = ((const float4*)m_lds)[tid];
}

extern "C" void kernel_launch(void* const* d_in, const int* in_sizes, int n_in,
                              void* d_out, int out_size, void* d_ws, size_t ws_size,
                              hipStream_t stream) {
  const float* J = (const float*)d_in[0];
  const float* h = (const float*)d_in[1];
  const float* m0 = (const float*)d_in[2];
  const int* idx = (const int*)d_in[3];
  const float* u = (const float*)d_in[4];
  float* out = (float*)d_out;

  double* thr = (double*)d_ws;                                        // 16384 f64
  double* I0 = (double*)((char*)d_ws + STEPS * sizeof(double));       // 4096 f64
  int* lastocc = (int*)((char*)d_ws + STEPS * sizeof(double)
                                    + N * sizeof(double));            // 16384 i32

  pre_kernel<<<dim3(STEPS / 256), dim3(256), 0, stream>>>(u, idx, thr, lastocc);
  init_field_kernel<<<dim3(N), dim3(256), 0, stream>>>(J, h, m0, I0);
  pbit_kernel<<<dim3(1), dim3(MBLK), 0, stream>>>(J, m0, idx, thr, lastocc, I0, out);
}

// Round 8
// 2776.811 us; speedup vs baseline: 1.0402x; 1.0402x over previous
//
#include <hip/hip_runtime.h>
#include <math.h>

#define N 4096
#define STEPS 16384
#define CHUNK 32
#define NCHUNK (STEPS / CHUNK)
#define MBLK 1024
#define SST 36   // padded col stride (floats) for ST: 144B = 16B-aligned

// Workgroup barrier that does NOT drain vmcnt (LDS-only ordering between phases).
__device__ __forceinline__ void lgkm_barrier() {
  asm volatile("s_waitcnt lgkmcnt(0)\n\ts_barrier" ::: "memory");
}

// ---- prep: thr[t] = atanh(2u-1) in fp64; lastocc[t] = no later same-idx in chunk ----
__global__ __launch_bounds__(256) void pre_kernel(const float* __restrict__ u,
                                                  const int* __restrict__ idx,
                                                  double* __restrict__ thr,
                                                  int* __restrict__ lastocc) {
  int t = blockIdx.x * 256 + threadIdx.x;
  if (t < STEPS) {
    float r = 2.0f * u[t] - 1.0f;          // exact same fp32 rounding as reference
    double rd = (double)r;
    thr[t] = 0.5 * log((1.0 + rd) / (1.0 - rd));   // r=-1 -> -inf (tie->+1 matches ref)
    int cbase = t & ~(CHUNK - 1);
    int my = idx[t];
    int lo = 1;
    for (int tt = (t & (CHUNK - 1)) + 1; tt < CHUNK; ++tt)
      if (idx[cbase + tt] == my) { lo = 0; break; }
    lastocc[t] = lo;
  }
}

// ---- initial field: I0[row] = sum_k J[row,k]*m0[k] + h[row], fp64 accumulate ----
__global__ __launch_bounds__(256) void init_field_kernel(const float* __restrict__ J,
                                                         const float* __restrict__ h,
                                                         const float* __restrict__ m0,
                                                         double* __restrict__ I) {
  __shared__ double red[256];
  int row = blockIdx.x;
  const float4* Jr = (const float4*)(J + (size_t)row * N);
  const float4* mv = (const float4*)m0;
  double acc = 0.0;
  for (int q = threadIdx.x; q < N / 4; q += 256) {
    float4 a = Jr[q];
    float4 b = mv[q];
    acc += (double)(a.x * b.x) + (double)(a.y * b.y) +
           (double)(a.z * b.z) + (double)(a.w * b.w);
  }
  red[threadIdx.x] = acc;
  __syncthreads();
  for (int s = 128; s > 0; s >>= 1) {
    if (threadIdx.x < s) red[threadIdx.x] += red[threadIdx.x + s];
    __syncthreads();
  }
  if (threadIdx.x == 0) I[row] = red[0] + (double)h[row];
}

// ---- chunk-32 Glauber chain: 1 workgroup, 1024 threads, sequential 2-barrier ----
// P1: wave0 resolves 32 steps flip-driven (lanes 0-31 own one step; rounds =
//     flips+1). S(c) = 32x32 in-chunk couplings, gathered one chunk ahead
//     (issued P1-top, stored P1-bottom, double-buffered).
// P2: waves 1-15 apply the compacted flip list (<=16 fast path + rare overflow
//     pass). Pair-split fp64 field: thread u owns cols {2u,2u+1} in two halves
//     -> conflict-free b128 write-through. Wave0 owns no field.
__global__ __launch_bounds__(MBLK) void pbit_kernel(const float* __restrict__ J,
                                                    const float* __restrict__ m0,
                                                    const int* __restrict__ idx,
                                                    const double* __restrict__ thr,
                                                    const int* __restrict__ lastocc,
                                                    const double* __restrict__ I0,
                                                    float* __restrict__ out) {
  __shared__ __align__(16) double fld_lds[N];            // 32 KB master field
  __shared__ __align__(16) float m_lds[N];               // 16 KB spins
  __shared__ __align__(16) float ST_lds[2][CHUNK * SST]; // S dbuf (col-major)
  __shared__ __align__(16) int   pubi_lds[CHUNK];        // compacted flip rows
  __shared__ __align__(16) float pubd_lds[CHUNK];        // compacted deltas (+/-2)
  __shared__ int pubF_lds;                               // flip count

  const int tid = threadIdx.x;
  const bool isW0 = (tid < 64);

  // ---- field ownership (wave0 excluded): u = tid-64 in 0..959 owns cols
  // {2u, 2u+1} (0..1919) and {1920+2u, 1921+2u} (1920..3839);
  // threads 64..319 additionally own col 3840+u (3840..4095).
  const int u = tid - 64;
  const int cA = 2 * u;
  const int cB = 1920 + 2 * u;
  const int cE = 3840 + u;
  const bool hasE = (tid >= 64) && (tid < 320);
  double iA0 = 0, iA1 = 0, iB0 = 0, iB1 = 0, iE = 0;
  if (!isW0) {
    iA0 = I0[cA]; iA1 = I0[cA + 1];
    iB0 = I0[cB]; iB1 = I0[cB + 1];
    *(double2*)(&fld_lds[cA]) = make_double2(iA0, iA1);
    *(double2*)(&fld_lds[cB]) = make_double2(iB0, iB1);
    if (hasE) { iE = I0[cE]; fld_lds[cE] = iE; }
  }
  ((float4*)m_lds)[tid] = ((const float4*)m0)[tid];

  const int t32 = tid & 31;       // step slot within chunk (lanes 32-63 mirror)
  const int gt = tid >> 1;        // gather row slot (wave0: 0..31)
  const int gq = (tid & 1) * 16;  // gather col group (16 cols per lane)

  // wave0 pipeline registers
  int mi = 0, ni = 0, mlo = 0, nlo = 0;
  double mt = 0.0, nt = 0.0;
  int grow = 0;            // gather row for S(c+1)
  int gcol[16];            // gather cols for S(c+1)
  float mym = 0.0f;
#pragma unroll
  for (int k = 0; k < 16; ++k) gcol[k] = 0;

  if (isW0) {
    mi = idx[t32];          mt = thr[t32];          mlo = lastocc[t32];
    ni = idx[CHUNK + t32];  nt = thr[CHUNK + t32];  nlo = lastocc[CHUNK + t32];
    // stage gather addresses for S(1)
    grow = idx[CHUNK + gt];
#pragma unroll
    for (int k = 0; k < 16; ++k) gcol[k] = idx[CHUNK + gq + k];
    // synchronous gather S(0) -> buf 0
    {
      int r0 = idx[gt];
      const float* Jr = J + (size_t)r0 * N;
#pragma unroll
      for (int k = 0; k < 16; ++k) {
        int ck = idx[gq + k];
        ST_lds[0][(gq + k) * SST + gt] = Jr[ck];
      }
    }
    if (tid == 0) pubF_lds = 0;
  }
  __syncthreads();
  if (isW0) mym = m_lds[mi];

  for (int c = 0; c < NCHUNK; ++c) {
    // ---------------- P1: wave 0 resolves the 32 decisions ----------------
    if (isW0) {
      // 1) issue gather S(c+1) using staged addresses (no wait here)
      float gv[16];
      {
        const float* Jg = J + (size_t)grow * N;
#pragma unroll
        for (int k = 0; k < 16; ++k) gv[k] = Jg[gcol[k]];
      }
      // 2) issue staged loads for chunk c+2 (t-view + gather-addr view)
      int b2 = (c + 2) * CHUNK;
      if (b2 >= STEPS) b2 = 0;   // clamp: values unused on final chunks
      int Li = idx[b2 + t32];
      double Lt = thr[b2 + t32];
      int Llo = lastocc[b2 + t32];
      int Lrow = idx[b2 + gt];
      int Lcol[16];
#pragma unroll
      for (int k = 0; k < 16; ++k) Lcol[k] = idx[b2 + gq + k];
      // 3) read base field + this chunk's Scol (8 x float4) from buf[c&1]
      double Ival = fld_lds[mi];
      const float* sp = &ST_lds[c & 1][t32 * SST];
      float4 s0 = *(const float4*)(sp + 0);
      float4 s1 = *(const float4*)(sp + 4);
      float4 s2 = *(const float4*)(sp + 8);
      float4 s3 = *(const float4*)(sp + 12);
      float4 s4 = *(const float4*)(sp + 16);
      float4 s5 = *(const float4*)(sp + 20);
      float4 s6 = *(const float4*)(sp + 24);
      float4 s7 = *(const float4*)(sp + 28);
      // 4) flip-driven serial resolve: rounds = flips + 1
      float mcur = mym;
      float finals = 0.0f, finald = 0.0f;
      int conf = -1;
      bool locked = false;
      while (true) {
        float s = (Ival >= mt) ? 1.0f : -1.0f;   // I >= atanh(r) <=> tanh(I) >= r
        float dl = s - mcur;
        unsigned long long mask = __ballot(dl != 0.0f) & 0xFFFFFFFFull;
        mask &= (~0ull) << (conf + 1);
        if (mask == 0) {
          if (!locked) { finals = s; finald = 0.0f; }
          break;
        }
        int f = (int)__builtin_ctzll(mask);      // wave-uniform
        if (!locked && t32 <= f) { finals = s; finald = dl; locked = true; }
        float dl_f = __int_as_float(__builtin_amdgcn_readlane(__float_as_int(dl), f));
        float s_f  = __int_as_float(__builtin_amdgcn_readlane(__float_as_int(s), f));
        int   i_f  = __builtin_amdgcn_readlane(mi, f);
        // Scol[f] select: f is wave-uniform -> scalar branch/cselect tree
        float4 ph = (f & 16) ? ((f & 8) ? ((f & 4) ? s7 : s6) : ((f & 4) ? s5 : s4))
                             : ((f & 8) ? ((f & 4) ? s3 : s2) : ((f & 4) ? s1 : s0));
        float xcol = (f & 2) ? ((f & 1) ? ph.w : ph.z)
                             : ((f & 1) ? ph.y : ph.x);
        Ival += (double)(xcol * dl_f);            // exact product: dl in {-2,2}
        if (mi == i_f) mcur = s_f;                // in-chunk duplicate index
        conf = f;
      }
      // 5) publish: compacted flip list + m updates (last occurrence wins)
      unsigned long long fm = __ballot((tid < 32) && (finald != 0.0f));
      if (tid < 32) {
        if (finald != 0.0f) {
          int pos = __popcll(fm & ((1ull << t32) - 1ull));
          pubi_lds[pos] = mi;
          pubd_lds[pos] = finald;
        }
        if (mlo) m_lds[mi] = finals;
        if (tid == 0) pubF_lds = __popcll(fm);
      }
      // 6) store gathered S(c+1) into buf[(c+1)&1] (gather latency hidden by resolve)
#pragma unroll
      for (int k = 0; k < 16; ++k)
        ST_lds[(c + 1) & 1][(gq + k) * SST + gt] = gv[k];
      // 7) m gather for next chunk (after this chunk's m writes; in-order)
      mym = m_lds[ni];
      // 8) rotate pipeline registers
      mi = ni; mt = nt; mlo = nlo;
      ni = Li; nt = Lt; nlo = Llo;
      grow = Lrow;
#pragma unroll
      for (int k = 0; k < 16; ++k) gcol[k] = Lcol[k];
    }
    lgkm_barrier();

    // ---------------- P2: waves 1-15 apply the F flipped rows ----------------
    if (!isW0) {
      int F = pubF_lds;
      if (F > 0) {                         // uniform: skip flip-free chunks
        float aA0 = 0.f, aA1 = 0.f, aB0 = 0.f, aB1 = 0.f, aE = 0.f;
        // ---- fast path: rows 0..min(F,16) ----
        {
          int4 ra = *(const int4*)(pubi_lds + 0);
          int4 rb = *(const int4*)(pubi_lds + 4);
          int4 rc = *(const int4*)(pubi_lds + 8);
          int4 rd = *(const int4*)(pubi_lds + 12);
          float4 pa = *(const float4*)(pubd_lds + 0);
          float4 pb = *(const float4*)(pubd_lds + 4);
          float4 pc = *(const float4*)(pubd_lds + 8);
          float4 pd = *(const float4*)(pubd_lds + 12);
          int rows[16] = {ra.x, ra.y, ra.z, ra.w, rb.x, rb.y, rb.z, rb.w,
                          rc.x, rc.y, rc.z, rc.w, rd.x, rd.y, rd.z, rd.w};
          float dv[16] = {pa.x, pa.y, pa.z, pa.w, pb.x, pb.y, pb.z, pb.w,
                          pc.x, pc.y, pc.z, pc.w, pd.x, pd.y, pd.z, pd.w};
#pragma unroll
          for (int g = 0; g < 2; ++g) {
            float2 rA[8], rB[8]; float rE[8];
#pragma unroll
            for (int t = 8 * g; t < 8 * g + 8; ++t)
              if (t < F) {
                const float* rp = J + (size_t)rows[t] * N;
                rA[t - 8 * g] = *(const float2*)(rp + cA);
                rB[t - 8 * g] = *(const float2*)(rp + cB);
                if (hasE) rE[t - 8 * g] = rp[cE];
              }
#pragma unroll
            for (int t = 8 * g; t < 8 * g + 8; ++t)
              if (t < F) {
                aA0 += rA[t - 8 * g].x * dv[t]; aA1 += rA[t - 8 * g].y * dv[t];
                aB0 += rB[t - 8 * g].x * dv[t]; aB1 += rB[t - 8 * g].y * dv[t];
                if (hasE) aE += rE[t - 8 * g] * dv[t];
              }
          }
        }
        // ---- overflow pass (rare): rows 16..F ----
        if (F > 16) {
          int4 ra = *(const int4*)(pubi_lds + 16);
          int4 rb = *(const int4*)(pubi_lds + 20);
          int4 rc = *(const int4*)(pubi_lds + 24);
          int4 rd = *(const int4*)(pubi_lds + 28);
          float4 pa = *(const float4*)(pubd_lds + 16);
          float4 pb = *(const float4*)(pubd_lds + 20);
          float4 pc = *(const float4*)(pubd_lds + 24);
          float4 pd = *(const float4*)(pubd_lds + 28);
          int rows[16] = {ra.x, ra.y, ra.z, ra.w, rb.x, rb.y, rb.z, rb.w,
                          rc.x, rc.y, rc.z, rc.w, rd.x, rd.y, rd.z, rd.w};
          float dv[16] = {pa.x, pa.y, pa.z, pa.w, pb.x, pb.y, pb.z, pb.w,
                          pc.x, pc.y, pc.z, pc.w, pd.x, pd.y, pd.z, pd.w};
#pragma unroll
          for (int g = 0; g < 2; ++g) {
            float2 rA[8], rB[8]; float rE[8];
#pragma unroll
            for (int t = 8 * g; t < 8 * g + 8; ++t)
              if (16 + t < F) {
                const float* rp = J + (size_t)rows[t] * N;
                rA[t - 8 * g] = *(const float2*)(rp + cA);
                rB[t - 8 * g] = *(const float2*)(rp + cB);
                if (hasE) rE[t - 8 * g] = rp[cE];
              }
#pragma unroll
            for (int t = 8 * g; t < 8 * g + 8; ++t)
              if (16 + t < F) {
                aA0 += rA[t - 8 * g].x * dv[t]; aA1 += rA[t - 8 * g].y * dv[t];
                aB0 += rB[t - 8 * g].x * dv[t]; aB1 += rB[t - 8 * g].y * dv[t];
                if (hasE) aE += rE[t - 8 * g] * dv[t];
              }
          }
        }
        // chunk-local exact fp32 partials -> fp64 master, conflict-free write-through
        iA0 += (double)aA0; iA1 += (double)aA1;
        iB0 += (double)aB0; iB1 += (double)aB1;
        *(double2*)(&fld_lds[cA]) = make_double2(iA0, iA1);   // lane-contig 16B
        *(double2*)(&fld_lds[cB]) = make_double2(iB0, iB1);   // conflict-free
        if (hasE) { iE += (double)aE; fld_lds[cE] = iE; }
      }
    }
    lgkm_barrier();
  }

  ((float4*)out)[tid] = ((const float4*)m_lds)[tid];
}

extern "C" void kernel_launch(void* const* d_in, const int* in_sizes, int n_in,
                              void* d_out, int out_size, void* d_ws, size_t ws_size,
                              hipStream_t stream) {
  const float* J = (const float*)d_in[0];
  const float* h = (const float*)d_in[1];
  const float* m0 = (const float*)d_in[2];
  const int* idx = (const int*)d_in[3];
  const float* u = (const float*)d_in[4];
  float* out = (float*)d_out;

  double* thr = (double*)d_ws;                                        // 16384 f64
  double* I0 = (double*)((char*)d_ws + STEPS * sizeof(double));       // 4096 f64
  int* lastocc = (int*)((char*)d_ws + STEPS * sizeof(double)
                                    + N * sizeof(double));            // 16384 i32

  pre_kernel<<<dim3(STEPS / 256), dim3(256), 0, stream>>>(u, idx, thr, lastocc);
  init_field_kernel<<<dim3(N), dim3(256), 0, stream>>>(J, h, m0, I0);
  pbit_kernel<<<dim3(1), dim3(MBLK), 0, stream>>>(J, m0, idx, thr, lastocc, I0, out);
}

// Round 9
// 2279.989 us; speedup vs baseline: 1.2669x; 1.2179x over previous
//
#include <hip/hip_runtime.h>
#include <math.h>

#define N 4096
#define STEPS 16384
#define CHUNK 16
#define NCHUNK (STEPS / CHUNK)
#define MBLK 1024
#define SST 20   // padded col stride (floats) for ST: float4-aligned, 2-way max (free)

// Workgroup barrier that does NOT drain vmcnt (LDS-only ordering between phases).
__device__ __forceinline__ void lgkm_barrier() {
  asm volatile("s_waitcnt lgkmcnt(0)\n\ts_barrier" ::: "memory");
}

// ---- prep: thr[t] = atanh(2u-1) in fp64; lastocc[t] = no later same-idx in chunk ----
__global__ __launch_bounds__(256) void pre_kernel(const float* __restrict__ u,
                                                  const int* __restrict__ idx,
                                                  double* __restrict__ thr,
                                                  int* __restrict__ lastocc) {
  int t = blockIdx.x * 256 + threadIdx.x;
  if (t < STEPS) {
    float r = 2.0f * u[t] - 1.0f;          // exact same fp32 rounding as reference
    double rd = (double)r;
    thr[t] = 0.5 * log((1.0 + rd) / (1.0 - rd));   // r=-1 -> -inf (tie->+1 matches ref)
    int cbase = t & ~(CHUNK - 1);
    int my = idx[t];
    int lo = 1;
    for (int tt = (t & (CHUNK - 1)) + 1; tt < CHUNK; ++tt)
      if (idx[cbase + tt] == my) { lo = 0; break; }
    lastocc[t] = lo;
  }
}

// ---- initial field: I0[row] = sum_k J[row,k]*m0[k] + h[row], fp64 accumulate ----
__global__ __launch_bounds__(256) void init_field_kernel(const float* __restrict__ J,
                                                         const float* __restrict__ h,
                                                         const float* __restrict__ m0,
                                                         double* __restrict__ I) {
  __shared__ double red[256];
  int row = blockIdx.x;
  const float4* Jr = (const float4*)(J + (size_t)row * N);
  const float4* mv = (const float4*)m0;
  double acc = 0.0;
  for (int q = threadIdx.x; q < N / 4; q += 256) {
    float4 a = Jr[q];
    float4 b = mv[q];
    acc += (double)(a.x * b.x) + (double)(a.y * b.y) +
           (double)(a.z * b.z) + (double)(a.w * b.w);
  }
  red[threadIdx.x] = acc;
  __syncthreads();
  for (int s = 128; s > 0; s >>= 1) {
    if (threadIdx.x < s) red[threadIdx.x] += red[threadIdx.x + s];
    __syncthreads();
  }
  if (threadIdx.x == 0) I[row] = red[0] + (double)h[row];
}

// ---- chunk-resolved Glauber chain: 1 workgroup, 1024 threads ----
// P1: wave0 resolves 16 steps flip-driven (rounds = flips+1), NO global gathers
//     on its chain (S was staged by the gatherer waves last chunk).
// P2: waves 1-15 apply the compacted flip list (contiguous pair-split row
//     loads); threads 512-767 ADDITIONALLY gather S(c+1) one element each
//     (the divergent-gather pipe occupancy overlaps the apply exposure).
// Field: conflict-free pair-split fp64 ownership, LDS write-through.
// Barriers are lgkm-only (vector loads survive them).
__global__ __launch_bounds__(MBLK) void pbit_kernel(const float* __restrict__ J,
                                                    const float* __restrict__ m0,
                                                    const int* __restrict__ idx,
                                                    const double* __restrict__ thr,
                                                    const int* __restrict__ lastocc,
                                                    const double* __restrict__ I0,
                                                    float* __restrict__ out) {
  __shared__ __align__(16) double fld_lds[N];          // 32 KB master field
  __shared__ __align__(16) float m_lds[N];             // 16 KB spins
  __shared__ __align__(16) float ST_lds[CHUNK * SST];  // ST[t*SST+j] = J[idx_j][idx_t]
  __shared__ __align__(16) int   pubi_lds[CHUNK];      // compacted flip rows
  __shared__ __align__(16) float pubd_lds[CHUNK];      // compacted deltas (+/-2)
  __shared__ int pubF_lds;                             // flip count

  const int tid = threadIdx.x;
  const bool isW0 = (tid < 64);

  // ---- field ownership (wave0 excluded): u = tid-64 in 0..959 owns cols
  // {2u,2u+1} (0..1919) and {1920+2u,1921+2u} (1920..3839);
  // threads 64..319 additionally own col 3840+u.
  const int u = tid - 64;
  const int cA = 2 * u;
  const int cB = 1920 + 2 * u;
  const int cE = 3840 + u;
  const bool hasE = (tid >= 64) && (tid < 320);
  double iA0 = 0, iA1 = 0, iB0 = 0, iB1 = 0, iE = 0;
  if (!isW0) {
    iA0 = I0[cA]; iA1 = I0[cA + 1];
    iB0 = I0[cB]; iB1 = I0[cB + 1];
    *(double2*)(&fld_lds[cA]) = make_double2(iA0, iA1);
    *(double2*)(&fld_lds[cB]) = make_double2(iB0, iB1);
    if (hasE) { iE = I0[cE]; fld_lds[cE] = iE; }
  }
  ((float4*)m_lds)[tid] = ((const float4*)m0)[tid];

  const int t16 = tid & 15;       // wave0: step slot within chunk

  // ---- S gatherers: threads 512..767, one S element each ----
  // k = tid-512: j = k&15 (J-row slot), t = k>>4 (chunk-step col slot)
  // ST[t*SST+j] = J[idx_j][idx_t]
  const bool isG = (tid >= 512) && (tid < 768);
  const int k = tid - 512;
  const int kj = k & 15;
  const int kt = k >> 4;
  int gRow = 0, gCol = 0;         // staged J element address for S(c+1)

  if (isG) {
    // synchronous gather S(0)
    int i_j = idx[kj];
    int i_t = idx[kt];
    ST_lds[kt * SST + kj] = J[(size_t)i_j * N + i_t];
    // stage addresses for S(1)
    gRow = idx[CHUNK + kj];
    gCol = idx[CHUNK + kt];
  }

  // wave0 pipeline registers (t16-view staged two chunks deep)
  int mi = 0, ni = 0, mlo = 0, nlo = 0;
  double mt = 0.0, nt = 0.0;
  float mym = 0.0f;
  if (isW0) {
    mi = idx[t16];          mt = thr[t16];          mlo = lastocc[t16];
    ni = idx[CHUNK + t16];  nt = thr[CHUNK + t16];  nlo = lastocc[CHUNK + t16];
    if (tid == 0) pubF_lds = 0;
  }
  __syncthreads();
  if (isW0) mym = m_lds[mi];

  for (int c = 0; c < NCHUNK; ++c) {
    // ---------------- P1: wave 0 resolves the 16 decisions ----------------
    if (isW0) {
      // staged loads for chunk c+2 (small, coalesced; off the critical chain)
      int b2 = (c + 2) * CHUNK;
      if (b2 >= STEPS) b2 = 0;   // clamp: values unused on final chunks
      int Li = idx[b2 + t16];
      double Lt = thr[b2 + t16];
      int Llo = lastocc[b2 + t16];
      // base field + this chunk's coupling column (gathered last chunk by waves 8-11)
      double Ival = fld_lds[mi];
      const float* sp = &ST_lds[t16 * SST];
      float4 sa = *(const float4*)(sp + 0);
      float4 sb = *(const float4*)(sp + 4);
      float4 sc = *(const float4*)(sp + 8);
      float4 sd = *(const float4*)(sp + 12);
      // flip-driven serial resolve: rounds = flips + 1
      float mcur = mym;
      float finals = 0.0f, finald = 0.0f;
      int conf = -1;
      bool locked = false;
      while (true) {
        float s = (Ival >= mt) ? 1.0f : -1.0f;   // I >= atanh(r) <=> tanh(I) >= r
        float dl = s - mcur;
        unsigned long long mask = __ballot(dl != 0.0f) & 0xFFFFull;
        mask &= (~0ull) << (conf + 1);
        if (mask == 0) {
          if (!locked) { finals = s; finald = 0.0f; }
          break;
        }
        int f = (int)__builtin_ctzll(mask);      // wave-uniform
        if (!locked && t16 <= f) { finals = s; finald = dl; locked = true; }
        float dl_f = __int_as_float(__builtin_amdgcn_readlane(__float_as_int(dl), f));
        float s_f  = __int_as_float(__builtin_amdgcn_readlane(__float_as_int(s), f));
        int   i_f  = __builtin_amdgcn_readlane(mi, f);
        // branchless Scol[f] select (f uniform)
        float4 ph = (f & 8) ? ((f & 4) ? sd : sc) : ((f & 4) ? sb : sa);
        float xcol = (f & 2) ? ((f & 1) ? ph.w : ph.z)
                             : ((f & 1) ? ph.y : ph.x);
        Ival += (double)(xcol * dl_f);            // exact product: dl in {-2,2}
        if (mi == i_f) mcur = s_f;                // in-chunk duplicate index
        conf = f;
      }
      // publish: compacted flip list + m updates (last occurrence wins)
      unsigned long long fm = __ballot((tid < 16) && (finald != 0.0f));
      if (tid < 16) {
        if (finald != 0.0f) {
          int pos = __popcll(fm & ((1ull << t16) - 1ull));
          pubi_lds[pos] = mi;
          pubd_lds[pos] = finald;
        }
        if (mlo) m_lds[mi] = finals;
        if (tid == 0) pubF_lds = __popcll(fm);
      }
      // m gather for next chunk (after this chunk's m writes; same wave, in-order)
      mym = m_lds[ni];
      // rotate pipeline registers
      mi = ni; mt = nt; mlo = nlo;
      ni = Li; nt = Lt; nlo = Llo;
    }
    lgkm_barrier();

    // ---------- P2: waves 1-15 apply F rows; waves 8-11 gather S(c+1) ----------
    if (!isW0) {
      float gval = 0.0f;
      int nRow = 0, nCol = 0;
      if (isG) {
        // issue the divergent S(c+1) element load (overlaps apply exposure)
        gval = J[(size_t)gRow * N + gCol];
        // stage addresses for S(c+2)
        int b2 = (c + 2) * CHUNK;
        if (b2 >= STEPS) b2 = 0;
        nRow = idx[b2 + kj];
        nCol = idx[b2 + kt];
      }
      int F = pubF_lds;
      if (F > 0) {                         // uniform: skip flip-free chunks
        int4 ra = *(const int4*)(pubi_lds + 0);
        int4 rb = *(const int4*)(pubi_lds + 4);
        int4 rc = *(const int4*)(pubi_lds + 8);
        int4 rd = *(const int4*)(pubi_lds + 12);
        float4 pa = *(const float4*)(pubd_lds + 0);
        float4 pb = *(const float4*)(pubd_lds + 4);
        float4 pc = *(const float4*)(pubd_lds + 8);
        float4 pd = *(const float4*)(pubd_lds + 12);
        int rows[CHUNK] = {ra.x, ra.y, ra.z, ra.w, rb.x, rb.y, rb.z, rb.w,
                           rc.x, rc.y, rc.z, rc.w, rd.x, rd.y, rd.z, rd.w};
        float dv[CHUNK] = {pa.x, pa.y, pa.z, pa.w, pb.x, pb.y, pb.z, pb.w,
                           pc.x, pc.y, pc.z, pc.w, pd.x, pd.y, pd.z, pd.w};
        float aA0 = 0.f, aA1 = 0.f, aB0 = 0.f, aB1 = 0.f, aE = 0.f;
#pragma unroll
        for (int g = 0; g < 2; ++g) {
          float2 rA[8], rB[8]; float rE[8];
#pragma unroll
          for (int t = 8 * g; t < 8 * g + 8; ++t)
            if (t < F) {
              const float* rp = J + (size_t)rows[t] * N;
              rA[t - 8 * g] = *(const float2*)(rp + cA);
              rB[t - 8 * g] = *(const float2*)(rp + cB);
              if (hasE) rE[t - 8 * g] = rp[cE];
            }
#pragma unroll
          for (int t = 8 * g; t < 8 * g + 8; ++t)
            if (t < F) {
              aA0 += rA[t - 8 * g].x * dv[t]; aA1 += rA[t - 8 * g].y * dv[t];
              aB0 += rB[t - 8 * g].x * dv[t]; aB1 += rB[t - 8 * g].y * dv[t];
              if (hasE) aE += rE[t - 8 * g] * dv[t];
            }
        }
        // chunk-local exact fp32 partials -> fp64 master, conflict-free write-through
        iA0 += (double)aA0; iA1 += (double)aA1;
        iB0 += (double)aB0; iB1 += (double)aB1;
        *(double2*)(&fld_lds[cA]) = make_double2(iA0, iA1);   // lane-contig 16B
        *(double2*)(&fld_lds[cB]) = make_double2(iB0, iB1);   // conflict-free
        if (hasE) { iE += (double)aE; fld_lds[cE] = iE; }
      }
      if (isG) {
        // store S(c+1) (waits this chunk's gather load; read by P1(c+1) after barrier)
        ST_lds[kt * SST + kj] = gval;
        gRow = nRow; gCol = nCol;
      }
    }
    lgkm_barrier();
  }

  ((float4*)out)[tid] = ((const float4*)m_lds)[tid];
}

extern "C" void kernel_launch(void* const* d_in, const int* in_sizes, int n_in,
                              void* d_out, int out_size, void* d_ws, size_t ws_size,
                              hipStream_t stream) {
  const float* J = (const float*)d_in[0];
  const float* h = (const float*)d_in[1];
  const float* m0 = (const float*)d_in[2];
  const int* idx = (const int*)d_in[3];
  const float* u = (const float*)d_in[4];
  float* out = (float*)d_out;

  double* thr = (double*)d_ws;                                        // 16384 f64
  double* I0 = (double*)((char*)d_ws + STEPS * sizeof(double));       // 4096 f64
  int* lastocc = (int*)((char*)d_ws + STEPS * sizeof(double)
                                    + N * sizeof(double));            // 16384 i32

  pre_kernel<<<dim3(STEPS / 256), dim3(256), 0, stream>>>(u, idx, thr, lastocc);
  init_field_kernel<<<dim3(N), dim3(256), 0, stream>>>(J, h, m0, I0);
  pbit_kernel<<<dim3(1), dim3(MBLK), 0, stream>>>(J, m0, idx, thr, lastocc, I0, out);
}